// Round 3
// baseline (17897.464 us; speedup 1.0000x reference)
//
#include <hip/hip_runtime.h>
#include <hip/hip_bf16.h>

#define H 256
#define T_TOTAL 2048
#define BATCH 32
#define G3 768

typedef _Float16 h2 __attribute__((ext_vector_type(2)));
typedef _Float16 f16x4 __attribute__((ext_vector_type(4)));
typedef _Float16 f16x8 __attribute__((ext_vector_type(8)));

union f16x8_view {
    f16x8 v;
    h2 p[4];
};

__device__ __forceinline__ float sigf(float x) {
    return 1.0f / (1.0f + __expf(-x));
}
__device__ __forceinline__ float tanhfast(float x) {
    return 2.0f / (1.0f + __expf(-2.0f * x)) - 1.0f;
}

// ---------------------------------------------------------------------------
// Kernel 1: GI = X @ w_ih.T + b_ih   (parallel over all (b,t) rows)
// X: [BATCH, T_TOTAL, H] fp32 ; w_ih: [G3, H] fp32 ; out gi: f16 [BATCH, CT, G3]
// 64x64 tile, K staged in LDS transposed ([k][row]) so inner reads are b128.
// ---------------------------------------------------------------------------
__global__ __launch_bounds__(256) void gi_gemm(
    const float* __restrict__ x, const float* __restrict__ w_ih,
    const float* __restrict__ b_ih, _Float16* __restrict__ gi,
    int t0, int CT, int nrt)
{
    __shared__ float As[64][68];  // [k][row]   (+4 pad: keeps 16B align, spreads banks)
    __shared__ float Bs[64][68];  // [k][col]
    const int tid = threadIdx.x;
    const int bi = blockIdx.x / nrt;   // batch index
    const int ti = blockIdx.x % nrt;   // row-tile within chunk
    const int jt = blockIdx.y;         // col tile (0..11)
    const int ty = tid >> 4, tx = tid & 15;

    float acc[4][4] = {};

    for (int k0 = 0; k0 < H; k0 += 64) {
        __syncthreads();
        // stage A (x rows) and B (w_ih rows) transposed into LDS
        #pragma unroll
        for (int l = 0; l < 4; ++l) {
            int idx = tid + l * 256;
            int r = idx >> 4;             // local row / local col
            int k4 = (idx & 15) << 2;     // k offset
            int tl = ti * 64 + r;
            float4 v = make_float4(0.f, 0.f, 0.f, 0.f);
            if (tl < CT)
                v = *(const float4*)&x[((size_t)bi * T_TOTAL + t0 + tl) * H + k0 + k4];
            As[k4 + 0][r] = v.x; As[k4 + 1][r] = v.y;
            As[k4 + 2][r] = v.z; As[k4 + 3][r] = v.w;
            float4 w = *(const float4*)&w_ih[((size_t)jt * 64 + r) * H + k0 + k4];
            Bs[k4 + 0][r] = w.x; Bs[k4 + 1][r] = w.y;
            Bs[k4 + 2][r] = w.z; Bs[k4 + 3][r] = w.w;
        }
        __syncthreads();
        #pragma unroll
        for (int kk = 0; kk < 64; ++kk) {
            float a[4], b[4];
            *(float4*)a = *(const float4*)&As[kk][ty * 4];
            *(float4*)b = *(const float4*)&Bs[kk][tx * 4];
            #pragma unroll
            for (int mi = 0; mi < 4; ++mi)
                #pragma unroll
                for (int ni = 0; ni < 4; ++ni)
                    acc[mi][ni] = fmaf(a[mi], b[ni], acc[mi][ni]);
        }
    }

    float4 bias = *(const float4*)&b_ih[jt * 64 + tx * 4];
    #pragma unroll
    for (int mi = 0; mi < 4; ++mi) {
        int tl = ti * 64 + ty * 4 + mi;
        if (tl < CT) {
            f16x4 o;
            o[0] = (_Float16)(acc[mi][0] + bias.x);
            o[1] = (_Float16)(acc[mi][1] + bias.y);
            o[2] = (_Float16)(acc[mi][2] + bias.z);
            o[3] = (_Float16)(acc[mi][3] + bias.w);
            *(f16x4*)&gi[((size_t)bi * CT + tl) * G3 + jt * 64 + tx * 4] = o;
        }
    }
}

// ---------------------------------------------------------------------------
// Kernel 2: sequential GRU recurrence. One workgroup per batch row.
// Thread j owns w_hh rows {j, j+256, j+512} as f16 in registers (384 VGPR).
// h broadcast from LDS (f16), fp32 master copy of h[j] stays in a register.
// Per layer: 384 x v_dot2_f32_f16 + gates + 1 barrier.
// ---------------------------------------------------------------------------
__global__ __launch_bounds__(256, 1) void gru_seq(
    const _Float16* __restrict__ gi, const float* __restrict__ w_hh,
    const float* __restrict__ b_hh, float* __restrict__ hstate,
    float* __restrict__ out, int t0, int CT)
{
    const int b = blockIdx.x;
    const int j = threadIdx.x;
    __shared__ __align__(16) _Float16 hsh[2][H];

    // --- load + convert this thread's 3 weight rows into registers ---
    h2 w0[128], w1[128], w2[128];
    {
        const float4* p0 = (const float4*)(w_hh + (size_t)j * H);
        const float4* p1 = (const float4*)(w_hh + (size_t)(j + 256) * H);
        const float4* p2 = (const float4*)(w_hh + (size_t)(j + 512) * H);
        #pragma unroll
        for (int q = 0; q < 64; ++q) {
            float4 v0 = p0[q];
            w0[2 * q]     = h2{(_Float16)v0.x, (_Float16)v0.y};
            w0[2 * q + 1] = h2{(_Float16)v0.z, (_Float16)v0.w};
            float4 v1 = p1[q];
            w1[2 * q]     = h2{(_Float16)v1.x, (_Float16)v1.y};
            w1[2 * q + 1] = h2{(_Float16)v1.z, (_Float16)v1.w};
            float4 v2 = p2[q];
            w2[2 * q]     = h2{(_Float16)v2.x, (_Float16)v2.y};
            w2[2 * q + 1] = h2{(_Float16)v2.z, (_Float16)v2.w};
        }
    }
    const float bh0 = b_hh[j], bh1 = b_hh[j + 256], bh2 = b_hh[j + 512];

    float hj = hstate[b * H + j];
    hsh[0][j] = (_Float16)hj;
    __syncthreads();

    int buf = 0;
    const _Float16* g = gi + (size_t)b * CT * G3;
    float* o = out + ((size_t)t0 * BATCH + b) * H + j;

    for (int tl = 0; tl < CT; ++tl) {
        // gi triplet — identical for both layer applications at this t
        float gr = (float)g[j];
        float gz = (float)g[j + 256];
        float gn = (float)g[j + 512];
        g += G3;

        #pragma unroll
        for (int layer = 0; layer < 2; ++layer) {
            float a0 = bh0, a1 = bh1, a2 = bh2;
            const f16x8* hp = (const f16x8*)hsh[buf];
            #pragma unroll
            for (int kk = 0; kk < 32; ++kk) {
                f16x8_view hv;
                hv.v = hp[kk];               // broadcast b128 read
                #pragma unroll
                for (int p = 0; p < 4; ++p) {
                    h2 hh = hv.p[p];
                    a0 = __builtin_amdgcn_fdot2(w0[kk * 4 + p], hh, a0, false);
                    a1 = __builtin_amdgcn_fdot2(w1[kk * 4 + p], hh, a1, false);
                    a2 = __builtin_amdgcn_fdot2(w2[kk * 4 + p], hh, a2, false);
                }
            }
            float r = sigf(gr + a0);
            float z = sigf(gz + a1);
            float n = tanhfast(gn + r * a2);
            hj = (1.0f - z) * n + z * hj;
            buf ^= 1;
            hsh[buf][j] = (_Float16)hj;
            __syncthreads();
        }
        *o = hj;                 // out[t][b][j]
        o += BATCH * H;
    }
    hstate[b * H + j] = hj;      // persist for next chunk
}

// ---------------------------------------------------------------------------
extern "C" void kernel_launch(void* const* d_in, const int* in_sizes, int n_in,
                              void* d_out, int out_size, void* d_ws, size_t ws_size,
                              hipStream_t stream) {
    const float* x    = (const float*)d_in[1];
    const float* h0   = (const float*)d_in[2];
    const float* w_ih = (const float*)d_in[3];
    const float* w_hh = (const float*)d_in[4];
    const float* b_ih = (const float*)d_in[5];
    const float* b_hh = (const float*)d_in[6];
    float* out = (float*)d_out;

    // ws layout: [0,32KB) h-state fp32 ; rest: gi chunk (f16)
    float* hstate = (float*)d_ws;
    _Float16* gi = (_Float16*)((char*)d_ws + 32768);
    size_t avail = (ws_size > 32768) ? ws_size - 32768 : 0;
    long long maxCT = (long long)(avail / ((size_t)BATCH * G3 * sizeof(_Float16)));
    if (maxCT < 1) maxCT = 1;
    if (maxCT > T_TOTAL) maxCT = T_TOTAL;

    (void)hipMemcpyAsync(hstate, h0, BATCH * H * sizeof(float),
                         hipMemcpyDeviceToDevice, stream);

    for (int t0 = 0; t0 < T_TOTAL; t0 += (int)maxCT) {
        int CT = (T_TOTAL - t0 < (int)maxCT) ? (T_TOTAL - t0) : (int)maxCT;
        int nrt = (CT + 63) / 64;
        dim3 grid(BATCH * nrt, G3 / 64);
        gi_gemm<<<grid, 256, 0, stream>>>(x, w_ih, b_ih, gi, t0, CT, nrt);
        gru_seq<<<BATCH, 256, 0, stream>>>(gi, w_hh, b_hh, hstate, out, t0, CT);
    }
}

// Round 8
// 5138.226 us; speedup vs baseline: 3.4832x; 3.4832x over previous
//
#include <hip/hip_runtime.h>
#include <hip/hip_bf16.h>

#define H 256
#define T_TOTAL 2048
#define BATCH 32
#define G3 768

typedef _Float16 h2 __attribute__((ext_vector_type(2)));
typedef _Float16 f16x4 __attribute__((ext_vector_type(4)));
typedef _Float16 f16x8 __attribute__((ext_vector_type(8)));

union f16x8_view {
    f16x8 v;
    h2 p[4];
};

__device__ __forceinline__ float sigf(float x) {
    return 1.0f / (1.0f + __expf(-x));
}
__device__ __forceinline__ float tanhfast(float x) {
    return 2.0f / (1.0f + __expf(-2.0f * x)) - 1.0f;
}

// ---------------------------------------------------------------------------
// Kernel 1: GI = X @ w_ih.T + b_ih   (parallel over all (b,t) rows)
// ---------------------------------------------------------------------------
__global__ __launch_bounds__(256) void gi_gemm(
    const float* __restrict__ x, const float* __restrict__ w_ih,
    const float* __restrict__ b_ih, _Float16* __restrict__ gi,
    int t0, int CT, int nrt)
{
    __shared__ float As[64][68];  // [k][row]
    __shared__ float Bs[64][68];  // [k][col]
    const int tid = threadIdx.x;
    const int bi = blockIdx.x / nrt;
    const int ti = blockIdx.x % nrt;
    const int jt = blockIdx.y;
    const int ty = tid >> 4, tx = tid & 15;

    float acc[4][4] = {};

    for (int k0 = 0; k0 < H; k0 += 64) {
        __syncthreads();
        #pragma unroll
        for (int l = 0; l < 4; ++l) {
            int idx = tid + l * 256;
            int r = idx >> 4;
            int k4 = (idx & 15) << 2;
            int tl = ti * 64 + r;
            float4 v = make_float4(0.f, 0.f, 0.f, 0.f);
            if (tl < CT)
                v = *(const float4*)&x[((size_t)bi * T_TOTAL + t0 + tl) * H + k0 + k4];
            As[k4 + 0][r] = v.x; As[k4 + 1][r] = v.y;
            As[k4 + 2][r] = v.z; As[k4 + 3][r] = v.w;
            float4 w = *(const float4*)&w_ih[((size_t)jt * 64 + r) * H + k0 + k4];
            Bs[k4 + 0][r] = w.x; Bs[k4 + 1][r] = w.y;
            Bs[k4 + 2][r] = w.z; Bs[k4 + 3][r] = w.w;
        }
        __syncthreads();
        #pragma unroll
        for (int kk = 0; kk < 64; ++kk) {
            float a[4], b[4];
            *(float4*)a = *(const float4*)&As[kk][ty * 4];
            *(float4*)b = *(const float4*)&Bs[kk][tx * 4];
            #pragma unroll
            for (int mi = 0; mi < 4; ++mi)
                #pragma unroll
                for (int ni = 0; ni < 4; ++ni)
                    acc[mi][ni] = fmaf(a[mi], b[ni], acc[mi][ni]);
        }
    }

    float4 bias = *(const float4*)&b_ih[jt * 64 + tx * 4];
    #pragma unroll
    for (int mi = 0; mi < 4; ++mi) {
        int tl = ti * 64 + ty * 4 + mi;
        if (tl < CT) {
            f16x4 o;
            o[0] = (_Float16)(acc[mi][0] + bias.x);
            o[1] = (_Float16)(acc[mi][1] + bias.y);
            o[2] = (_Float16)(acc[mi][2] + bias.z);
            o[3] = (_Float16)(acc[mi][3] + bias.w);
            *(f16x4*)&gi[((size_t)bi * CT + tl) * G3 + jt * 64 + tx * 4] = o;
        }
    }
}

// ---------------------------------------------------------------------------
// Kernel 2: sequential GRU recurrence. One 512-thread WG per batch row.
// Lane pair (2j, 2j+1) splits the K dim of hidden-row j: each thread holds
// 3 gate-rows x 128 k-elems as f16 = 192 VGPRs (fits 256-class, NO SPILL),
// 8 waves = 2 waves/SIMD for latency hiding. Partials combine via
// __shfl_xor(.,1) (quad-perm DPP), no extra barrier.
// NOTE: n-gate hidden bias bh2 must sit INSIDE r*(...) — PyTorch GRU math.
// ---------------------------------------------------------------------------
__global__ __launch_bounds__(512, 2) void gru_seq(
    const _Float16* __restrict__ gi, const float* __restrict__ w_hh,
    const float* __restrict__ b_hh, float* __restrict__ hstate,
    float* __restrict__ out, int t0, int CT)
{
    const int b = blockIdx.x;
    const int tid = threadIdx.x;
    const int j = tid >> 1;          // hidden index owned
    const int half = tid & 1;        // which K-half
    __shared__ __align__(16) _Float16 hsh[2][H];

    // --- load + convert this thread's 3 half-rows into registers ---
    h2 w0[64], w1[64], w2[64];
    {
        const float4* p0 = (const float4*)(w_hh + (size_t)j * H + half * 128);
        const float4* p1 = (const float4*)(w_hh + (size_t)(j + 256) * H + half * 128);
        const float4* p2 = (const float4*)(w_hh + (size_t)(j + 512) * H + half * 128);
        #pragma unroll
        for (int q = 0; q < 32; ++q) {
            float4 v0 = p0[q];
            w0[2 * q]     = h2{(_Float16)v0.x, (_Float16)v0.y};
            w0[2 * q + 1] = h2{(_Float16)v0.z, (_Float16)v0.w};
            float4 v1 = p1[q];
            w1[2 * q]     = h2{(_Float16)v1.x, (_Float16)v1.y};
            w1[2 * q + 1] = h2{(_Float16)v1.z, (_Float16)v1.w};
            float4 v2 = p2[q];
            w2[2 * q]     = h2{(_Float16)v2.x, (_Float16)v2.y};
            w2[2 * q + 1] = h2{(_Float16)v2.z, (_Float16)v2.w};
        }
    }
    const float bh0 = b_hh[j], bh1 = b_hh[j + 256], bh2 = b_hh[j + 512];

    float hj = hstate[b * H + j];
    if (!half) hsh[0][j] = (_Float16)hj;
    __syncthreads();

    int buf = 0;
    const _Float16* g = gi + (size_t)b * CT * G3;
    float* o = out + ((size_t)t0 * BATCH + b) * H + j;

    for (int tl = 0; tl < CT; ++tl) {
        // gi triplet — identical for both layer applications at this t
        float gr = (float)g[j];
        float gz = (float)g[j + 256];
        float gn = (float)g[j + 512];
        g += G3;

        #pragma unroll
        for (int layer = 0; layer < 2; ++layer) {
            float a0 = 0.f, a1 = 0.f, a2 = 0.f;
            const f16x8* hp = (const f16x8*)&hsh[buf][half * 128];
            #pragma unroll
            for (int kk = 0; kk < 16; ++kk) {
                f16x8_view hv;
                hv.v = hp[kk];               // broadcast b128 read
                #pragma unroll
                for (int p = 0; p < 4; ++p) {
                    h2 hh = hv.p[p];
                    a0 = __builtin_amdgcn_fdot2(w0[kk * 4 + p], hh, a0, false);
                    a1 = __builtin_amdgcn_fdot2(w1[kk * 4 + p], hh, a1, false);
                    a2 = __builtin_amdgcn_fdot2(w2[kk * 4 + p], hh, a2, false);
                }
            }
            // combine K-halves across the lane pair (in-wave, cheap DPP)
            a0 += __shfl_xor(a0, 1);
            a1 += __shfl_xor(a1, 1);
            a2 += __shfl_xor(a2, 1);

            float r = sigf(gr + bh0 + a0);
            float z = sigf(gz + bh1 + a1);
            float n = tanhfast(gn + r * (bh2 + a2));   // bias INSIDE r*(...)
            hj = (1.0f - z) * n + z * hj;
            buf ^= 1;
            if (!half) hsh[buf][j] = (_Float16)hj;
            __syncthreads();
        }
        if (!half) *o = hj;          // out[t][b][j]
        o += BATCH * H;
    }
    if (!half) hstate[b * H + j] = hj;   // persist for next chunk
}

// ---------------------------------------------------------------------------
extern "C" void kernel_launch(void* const* d_in, const int* in_sizes, int n_in,
                              void* d_out, int out_size, void* d_ws, size_t ws_size,
                              hipStream_t stream) {
    const float* x    = (const float*)d_in[1];
    const float* h0   = (const float*)d_in[2];
    const float* w_ih = (const float*)d_in[3];
    const float* w_hh = (const float*)d_in[4];
    const float* b_ih = (const float*)d_in[5];
    const float* b_hh = (const float*)d_in[6];
    float* out = (float*)d_out;

    // ws layout: [0,32KB) h-state fp32 ; rest: gi chunk (f16)
    float* hstate = (float*)d_ws;
    _Float16* gi = (_Float16*)((char*)d_ws + 32768);
    size_t avail = (ws_size > 32768) ? ws_size - 32768 : 0;
    long long maxCT = (long long)(avail / ((size_t)BATCH * G3 * sizeof(_Float16)));
    if (maxCT < 1) maxCT = 1;
    if (maxCT > T_TOTAL) maxCT = T_TOTAL;

    (void)hipMemcpyAsync(hstate, h0, BATCH * H * sizeof(float),
                         hipMemcpyDeviceToDevice, stream);

    for (int t0 = 0; t0 < T_TOTAL; t0 += (int)maxCT) {
        int CT = (T_TOTAL - t0 < (int)maxCT) ? (T_TOTAL - t0) : (int)maxCT;
        int nrt = (CT + 63) / 64;
        dim3 grid(BATCH * nrt, G3 / 64);
        gi_gemm<<<grid, 256, 0, stream>>>(x, w_ih, b_ih, gi, t0, CT, nrt);
        gru_seq<<<BATCH, 512, 0, stream>>>(gi, w_hh, b_hh, hstate, out, t0, CT);
    }
}

// Round 9
// 5133.324 us; speedup vs baseline: 3.4865x; 1.0010x over previous
//
#include <hip/hip_runtime.h>
#include <hip/hip_bf16.h>

#define H 256
#define T_TOTAL 2048
#define BATCH 32
#define G3 768

typedef _Float16 h2 __attribute__((ext_vector_type(2)));
typedef _Float16 f16x4 __attribute__((ext_vector_type(4)));
typedef _Float16 f16x8 __attribute__((ext_vector_type(8)));

union f16x8_view {
    f16x8 v;
    h2 p[4];
};

__device__ __forceinline__ float sigf(float x) {
    return 1.0f / (1.0f + __expf(-x));
}
__device__ __forceinline__ float tanhfast(float x) {
    return 2.0f / (1.0f + __expf(-2.0f * x)) - 1.0f;
}

// ---------------------------------------------------------------------------
// Kernel 1: GI = X @ w_ih.T + b_ih   (parallel over all (b,t) rows)
// ---------------------------------------------------------------------------
__global__ __launch_bounds__(256) void gi_gemm(
    const float* __restrict__ x, const float* __restrict__ w_ih,
    const float* __restrict__ b_ih, _Float16* __restrict__ gi,
    int t0, int CT, int nrt)
{
    __shared__ float As[64][68];  // [k][row]
    __shared__ float Bs[64][68];  // [k][col]
    const int tid = threadIdx.x;
    const int bi = blockIdx.x / nrt;
    const int ti = blockIdx.x % nrt;
    const int jt = blockIdx.y;
    const int ty = tid >> 4, tx = tid & 15;

    float acc[4][4] = {};

    for (int k0 = 0; k0 < H; k0 += 64) {
        __syncthreads();
        #pragma unroll
        for (int l = 0; l < 4; ++l) {
            int idx = tid + l * 256;
            int r = idx >> 4;
            int k4 = (idx & 15) << 2;
            int tl = ti * 64 + r;
            float4 v = make_float4(0.f, 0.f, 0.f, 0.f);
            if (tl < CT)
                v = *(const float4*)&x[((size_t)bi * T_TOTAL + t0 + tl) * H + k0 + k4];
            As[k4 + 0][r] = v.x; As[k4 + 1][r] = v.y;
            As[k4 + 2][r] = v.z; As[k4 + 3][r] = v.w;
            float4 w = *(const float4*)&w_ih[((size_t)jt * 64 + r) * H + k0 + k4];
            Bs[k4 + 0][r] = w.x; Bs[k4 + 1][r] = w.y;
            Bs[k4 + 2][r] = w.z; Bs[k4 + 3][r] = w.w;
        }
        __syncthreads();
        #pragma unroll
        for (int kk = 0; kk < 64; ++kk) {
            float a[4], b[4];
            *(float4*)a = *(const float4*)&As[kk][ty * 4];
            *(float4*)b = *(const float4*)&Bs[kk][tx * 4];
            #pragma unroll
            for (int mi = 0; mi < 4; ++mi)
                #pragma unroll
                for (int ni = 0; ni < 4; ++ni)
                    acc[mi][ni] = fmaf(a[mi], b[ni], acc[mi][ni]);
        }
    }

    float4 bias = *(const float4*)&b_ih[jt * 64 + tx * 4];
    #pragma unroll
    for (int mi = 0; mi < 4; ++mi) {
        int tl = ti * 64 + ty * 4 + mi;
        if (tl < CT) {
            f16x4 o;
            o[0] = (_Float16)(acc[mi][0] + bias.x);
            o[1] = (_Float16)(acc[mi][1] + bias.y);
            o[2] = (_Float16)(acc[mi][2] + bias.z);
            o[3] = (_Float16)(acc[mi][3] + bias.w);
            *(f16x4*)&gi[((size_t)bi * CT + tl) * G3 + jt * 64 + tx * 4] = o;
        }
    }
}

// ---------------------------------------------------------------------------
// Kernel 2: sequential GRU recurrence. One 512-thread WG per batch row.
// Lane pair (2j, 2j+1) splits the K dim of hidden-row j: each thread holds
// 3 gate-rows x 128 k-elems as f16 = 192 VGPRs + ~40 working = ~232.
// __launch_bounds__(512, 1): relax VGPR cap to the 256 arch max so the
// weights STAY in registers (512,2 capped at 128 -> AGPR spill, 2x VALU).
// 8 waves = 2 waves/SIMD. Partials combine via __shfl_xor(.,1).
// NOTE: n-gate hidden bias bh2 must sit INSIDE r*(...) — PyTorch GRU math.
// ---------------------------------------------------------------------------
__global__ __launch_bounds__(512, 1) void gru_seq(
    const _Float16* __restrict__ gi, const float* __restrict__ w_hh,
    const float* __restrict__ b_hh, float* __restrict__ hstate,
    float* __restrict__ out, int t0, int CT)
{
    const int b = blockIdx.x;
    const int tid = threadIdx.x;
    const int j = tid >> 1;          // hidden index owned
    const int half = tid & 1;        // which K-half
    __shared__ __align__(16) _Float16 hsh[2][H];

    // --- load + convert this thread's 3 half-rows into registers ---
    h2 w0[64], w1[64], w2[64];
    {
        const float4* p0 = (const float4*)(w_hh + (size_t)j * H + half * 128);
        const float4* p1 = (const float4*)(w_hh + (size_t)(j + 256) * H + half * 128);
        const float4* p2 = (const float4*)(w_hh + (size_t)(j + 512) * H + half * 128);
        #pragma unroll
        for (int q = 0; q < 32; ++q) {
            float4 v0 = p0[q];
            w0[2 * q]     = h2{(_Float16)v0.x, (_Float16)v0.y};
            w0[2 * q + 1] = h2{(_Float16)v0.z, (_Float16)v0.w};
            float4 v1 = p1[q];
            w1[2 * q]     = h2{(_Float16)v1.x, (_Float16)v1.y};
            w1[2 * q + 1] = h2{(_Float16)v1.z, (_Float16)v1.w};
            float4 v2 = p2[q];
            w2[2 * q]     = h2{(_Float16)v2.x, (_Float16)v2.y};
            w2[2 * q + 1] = h2{(_Float16)v2.z, (_Float16)v2.w};
        }
    }
    const float bh0 = b_hh[j], bh1 = b_hh[j + 256], bh2 = b_hh[j + 512];

    float hj = hstate[b * H + j];
    if (!half) hsh[0][j] = (_Float16)hj;
    __syncthreads();

    int buf = 0;
    const _Float16* g = gi + (size_t)b * CT * G3;
    float* o = out + ((size_t)t0 * BATCH + b) * H + j;

    for (int tl = 0; tl < CT; ++tl) {
        // gi triplet — identical for both layer applications at this t
        float gr = (float)g[j];
        float gz = (float)g[j + 256];
        float gn = (float)g[j + 512];
        g += G3;

        #pragma unroll
        for (int layer = 0; layer < 2; ++layer) {
            float a0 = 0.f, a1 = 0.f, a2 = 0.f;
            const f16x8* hp = (const f16x8*)&hsh[buf][half * 128];
            #pragma unroll
            for (int kk = 0; kk < 16; ++kk) {
                f16x8_view hv;
                hv.v = hp[kk];               // broadcast b128 read
                #pragma unroll
                for (int p = 0; p < 4; ++p) {
                    h2 hh = hv.p[p];
                    a0 = __builtin_amdgcn_fdot2(w0[kk * 4 + p], hh, a0, false);
                    a1 = __builtin_amdgcn_fdot2(w1[kk * 4 + p], hh, a1, false);
                    a2 = __builtin_amdgcn_fdot2(w2[kk * 4 + p], hh, a2, false);
                }
            }
            // combine K-halves across the lane pair (in-wave, cheap DPP)
            a0 += __shfl_xor(a0, 1);
            a1 += __shfl_xor(a1, 1);
            a2 += __shfl_xor(a2, 1);

            float r = sigf(gr + bh0 + a0);
            float z = sigf(gz + bh1 + a1);
            float n = tanhfast(gn + r * (bh2 + a2));   // bias INSIDE r*(...)
            hj = (1.0f - z) * n + z * hj;
            buf ^= 1;
            if (!half) hsh[buf][j] = (_Float16)hj;
            __syncthreads();
        }
        if (!half) *o = hj;          // out[t][b][j]
        o += BATCH * H;
    }
    if (!half) hstate[b * H + j] = hj;   // persist for next chunk
}

// ---------------------------------------------------------------------------
extern "C" void kernel_launch(void* const* d_in, const int* in_sizes, int n_in,
                              void* d_out, int out_size, void* d_ws, size_t ws_size,
                              hipStream_t stream) {
    const float* x    = (const float*)d_in[1];
    const float* h0   = (const float*)d_in[2];
    const float* w_ih = (const float*)d_in[3];
    const float* w_hh = (const float*)d_in[4];
    const float* b_ih = (const float*)d_in[5];
    const float* b_hh = (const float*)d_in[6];
    float* out = (float*)d_out;

    // ws layout: [0,32KB) h-state fp32 ; rest: gi chunk (f16)
    float* hstate = (float*)d_ws;
    _Float16* gi = (_Float16*)((char*)d_ws + 32768);
    size_t avail = (ws_size > 32768) ? ws_size - 32768 : 0;
    long long maxCT = (long long)(avail / ((size_t)BATCH * G3 * sizeof(_Float16)));
    if (maxCT < 1) maxCT = 1;
    if (maxCT > T_TOTAL) maxCT = T_TOTAL;

    (void)hipMemcpyAsync(hstate, h0, BATCH * H * sizeof(float),
                         hipMemcpyDeviceToDevice, stream);

    for (int t0 = 0; t0 < T_TOTAL; t0 += (int)maxCT) {
        int CT = (T_TOTAL - t0 < (int)maxCT) ? (T_TOTAL - t0) : (int)maxCT;
        int nrt = (CT + 63) / 64;
        dim3 grid(BATCH * nrt, G3 / 64);
        gi_gemm<<<grid, 256, 0, stream>>>(x, w_ih, b_ih, gi, t0, CT, nrt);
        gru_seq<<<BATCH, 512, 0, stream>>>(gi, w_hh, b_hh, hstate, out, t0, CT);
    }
}